// Round 8
// baseline (251.562 us; speedup 1.0000x reference)
//
#include <hip/hip_runtime.h>
#include <stdint.h>

// Problem constants (B=4, S=1024, D_MODEL=1024, H=16, D_HEAD=64, D_FF=1024)
#define BSZ 4
#define SEQ 1024
#define DM 1024
#define NH 16
#define DH 64
#define ROWS (BSZ * SEQ)   // 4096
#define QS3 3072

typedef unsigned short u16;
typedef short bf16x8 __attribute__((ext_vector_type(8)));
typedef float f32x4 __attribute__((ext_vector_type(4)));

__device__ __forceinline__ float b2f(u16 u) {
    union { uint32_t i; float f; } v; v.i = ((uint32_t)u) << 16; return v.f;
}
__device__ __forceinline__ u16 f2b(float f) {
    union { float f; uint32_t i; } v; v.f = f;
    uint32_t u = v.i;
    return (u16)((u + 0x7FFFu + ((u >> 16) & 1u)) >> 16);  // RTNE
}
__device__ __forceinline__ u16 f2b_rh(float f) {           // round-half-up (f >= 0)
    union { float f; uint32_t i; } v; v.f = f;
    return (u16)((v.i + 0x8000u) >> 16);
}

// Blocked fragment-order layout for [R, K] GEMM operands (tile 128x32 = 8KB).
__device__ __forceinline__ size_t blk_idx(int row, int col, int nkt) {
    return (((size_t)((row >> 7) * nkt + (col >> 5))) << 12)
         + ((((row >> 4) & 7) * 64 + ((col >> 3) & 3) * 16 + (row & 15)) << 3)
         + (col & 7);
}

typedef const __attribute__((address_space(1))) void gv_t;
typedef __attribute__((address_space(3))) void lv_t;
__device__ __forceinline__ void gl_lds16(const void* g, void* l) {
    __builtin_amdgcn_global_load_lds((gv_t*)g, (lv_t*)l, 16, 0, 0);
}

// ---------------------------------------------------------------------------
// Per-block dtype detection (no separate dispatch, no flag buffer).
// ---------------------------------------------------------------------------
__device__ __forceinline__ int detect_isf(const uint32_t* __restrict__ x) {
    const int lane = threadIdx.x & 63;
    const uint4 wv = *(const uint4*)(x + lane * 4);
    uint32_t ws[4] = {wv.x, wv.y, wv.z, wv.w};
    int c = 0;
    #pragma unroll
    for (int j = 0; j < 4; ++j) {
        uint32_t lo = ws[j] & 0xFFFFu;
        uint32_t e = (lo >> 7) & 0xFF;
        if ((e >= 100 && e <= 140) || lo == 0) c++;
    }
    #pragma unroll
    for (int d = 1; d < 64; d <<= 1) c += __shfl_xor(c, d);
    return c < 128;   // fewer than half sane -> fp32 input
}

// ---------------------------------------------------------------------------
// Fused preprocessing: ONE dispatch (unchanged).
// ---------------------------------------------------------------------------
__global__ __launch_bounds__(256) void prep_all(
    const void* x_raw, const void* Wq, const void* Wk, const void* Wv,
    const void* Wo, const void* W1, const void* W2,
    const void* bq, const void* bk, const void* bv, const void* bo,
    const void* b1, const void* b2, const void* g1, const void* be1,
    const void* g2, const void* be2,
    u16* __restrict__ x_b, u16* __restrict__ WqkvB, u16* __restrict__ WoB,
    u16* __restrict__ W1B, u16* __restrict__ W2B, u16* __restrict__ vecs)
{
    const int bid = blockIdx.x, tid = threadIdx.x;
    const int isf = detect_isf((const uint32_t*)x_raw);

    if (bid < 2048) {                      // ---- x convert to blocked
        const int gid = bid * 256 + tid;
        const int tile = gid >> 9, c = gid & 511;
        const int p = tile >> 5, t = tile & 31;
        const int r = p * 128 + ((c >> 6) & 7) * 16 + (c & 15);
        const int k = t * 32 + ((c >> 4) & 3) * 8;
        union { uint4 q; u16 s[8]; } o;
        if (isf) {
            const float* s = (const float*)x_raw + (size_t)r * DM + k;
            float4 f0 = *(const float4*)s;
            float4 f1 = *(const float4*)(s + 4);
            o.s[0] = f2b(f0.x); o.s[1] = f2b(f0.y); o.s[2] = f2b(f0.z); o.s[3] = f2b(f0.w);
            o.s[4] = f2b(f1.x); o.s[5] = f2b(f1.y); o.s[6] = f2b(f1.z); o.s[7] = f2b(f1.w);
        } else {
            o.q = *(const uint4*)((const u16*)x_raw + (size_t)r * DM + k);
        }
        *(uint4*)&x_b[(size_t)gid * 8] = o.q;
        return;
    }
    if (bid >= 8192) {                     // ---- small vectors
        const int i = (bid - 8192) * 256 + tid;   // [0, 10240)
        const int seg = i >> 10, off = i & 1023;
        const void* srcs[10] = {bq, bk, bv, bo, b1, b2, g1, be1, g2, be2};
        const void* s = srcs[seg];
        vecs[i] = isf ? f2b(((const float*)s)[off]) : ((const u16*)s)[off];
        return;
    }

    // ---- weight transposes (32x32 LDS tile)
    const void* src; u16* dst; int R, C, n_off, bx, by, z;
    if (bid < 5120) {                      // QKV: [H,1024,64]
        const int which = (bid - 2048) >> 10;     // 0,1,2
        const int lb = (bid - 2048) & 1023;
        src = which == 0 ? Wq : (which == 1 ? Wk : Wv);
        dst = WqkvB; R = DM; C = DH; n_off = which * 1024;
        bx = lb & 1; by = (lb >> 1) & 31; z = lb >> 6;
    } else {                               // square: [1024,1024]
        const int which = (bid - 5120) >> 10;     // 0,1,2
        const int lb = (bid - 5120) & 1023;
        src = which == 0 ? Wo : (which == 1 ? W1 : W2);
        dst = which == 0 ? WoB : (which == 1 ? W1B : W2B);
        R = DM; C = DM; n_off = 0;
        bx = lb & 31; by = (lb >> 5) & 31; z = 0;
    }

    __shared__ u16 Ts[32][33];
    const int cb = bx * 32, rb = by * 32;
    const int tr = tid >> 3, tc4 = (tid & 7) * 4;
    const size_t sbase = (size_t)z * R * C;

    u16 v[4];
    if (isf) {
        const float* s = (const float*)src + sbase + (size_t)(rb + tr) * C + cb + tc4;
        float4 f = *(const float4*)s;
        v[0] = f2b(f.x); v[1] = f2b(f.y); v[2] = f2b(f.z); v[3] = f2b(f.w);
    } else {
        const u16* s = (const u16*)src + sbase + (size_t)(rb + tr) * C + cb + tc4;
        ushort4 f = *(const ushort4*)s;
        v[0] = f.x; v[1] = f.y; v[2] = f.z; v[3] = f.w;
    }
    #pragma unroll
    for (int j = 0; j < 4; ++j) Ts[tc4 + j][tr] = v[j];
    __syncthreads();

    if (tid < 128) {
        const int np = tid & 31, qp = tid >> 5;
        const int n = n_off + z * C + cb + np;
        const int k = rb + qp * 8;
        union { uint4 q; u16 s[8]; } o;
        #pragma unroll
        for (int j = 0; j < 8; ++j) o.s[j] = Ts[np][qp * 8 + j];
        *(uint4*)&dst[blk_idx(n, k, 32)] = o.q;
    }
}

// ---------------------------------------------------------------------------
// QKV GEMM: blocked A,B; 128x128 tile; triple-buffered counted-vmcnt
// pipeline (depth-2). XCD-chunked swizzle (validated round 7: -9us family).
// ---------------------------------------------------------------------------
__global__ __launch_bounds__(256) void gemm_qkv(
    const u16* __restrict__ Ab, const u16* __restrict__ Bb,
    const u16* __restrict__ bias,
    u16* __restrict__ Qblk, u16* __restrict__ Kblk, u16* __restrict__ Vblk)
{
    __shared__ uint4 smem4[3072];                 // A 3x8KB + B 3x8KB = 48KB
    u16* As = (u16*)smem4;
    u16* Bs = (u16*)smem4 + 12288;
    u16* Cs = (u16*)smem4;                        // [128][136] after loop

    const int tid = threadIdx.x;
    const int w = tid >> 6, lane = tid & 63;
    const int l16 = lane & 15, quad = lane >> 4;
    const int wr = w >> 1, wc = w & 1;

    // XCD-chunked swizzle (grid 768 = 96 blocks/XCD, 768%8==0 -> bijective)
    const int fid = blockIdx.x;
    const int xcd = fid & 7, t = fid >> 3;        // t in [0,96)
    const int byi = ((xcd & 3) << 3) + (t & 7);   // M-panel [0,32)
    const int bxi = (xcd >> 2) * 12 + (t >> 3);   // N-panel [0,24)
    const int bm = byi * 128, bn = bxi * 128;
    const int nkt = 32;

    const u16* At = Ab + ((size_t)(bm >> 7) * nkt << 12);
    const u16* Bt = Bb + ((size_t)(bn >> 7) * nkt << 12);

    f32x4 acc[4][4];
    #pragma unroll
    for (int i = 0; i < 4; ++i)
        #pragma unroll
        for (int j = 0; j < 4; ++j)
            acc[i][j] = (f32x4){0.f, 0.f, 0.f, 0.f};

#define STAGE_QKV(t_, bf) do {                                             \
        const size_t tb_ = (size_t)(t_) << 12;                             \
        gl_lds16(&At[tb_ + (w * 64 + lane) * 8],       As + (bf) * 4096 + w * 512);        \
        gl_lds16(&At[tb_ + (256 + w * 64 + lane) * 8], As + (bf) * 4096 + 2048 + w * 512); \
        gl_lds16(&Bt[tb_ + (w * 64 + lane) * 8],       Bs + (bf) * 4096 + w * 512);        \
        gl_lds16(&Bt[tb_ + (256 + w * 64 + lane) * 8], Bs + (bf) * 4096 + 2048 + w * 512); \
    } while (0)

    STAGE_QKV(0, 0);
    STAGE_QKV(1, 1);
    asm volatile("s_waitcnt vmcnt(4)" ::: "memory");   // tile 0 landed
    __builtin_amdgcn_s_barrier();

    int cur = 0, nb = 2;
    for (int kt = 0; kt < nkt; ++kt) {
        if (kt + 2 < nkt) STAGE_QKV(kt + 2, nb);

        bf16x8 a[4], b[4];
        #pragma unroll
        for (int i = 0; i < 4; ++i)
            a[i] = *(const bf16x8*)&As[cur * 4096 + (((wr * 4 + i) * 64) + quad * 16 + l16) * 8];
        #pragma unroll
        for (int j = 0; j < 4; ++j)
            b[j] = *(const bf16x8*)&Bs[cur * 4096 + (((wc * 4 + j) * 64) + quad * 16 + l16) * 8];

        #pragma unroll
        for (int i = 0; i < 4; ++i)
            #pragma unroll
            for (int j = 0; j < 4; ++j)
                acc[i][j] = __builtin_amdgcn_mfma_f32_16x16x32_bf16(a[i], b[j], acc[i][j], 0, 0, 0);

        if (kt + 2 < nkt) {
            asm volatile("s_waitcnt vmcnt(4)" ::: "memory");
            __builtin_amdgcn_s_barrier();
        } else if (kt + 1 < nkt) {
            asm volatile("s_waitcnt vmcnt(0)" ::: "memory");
            __builtin_amdgcn_s_barrier();
        }
        cur = cur == 2 ? 0 : cur + 1;
        nb  = nb  == 2 ? 0 : nb + 1;
    }
    __syncthreads();
#undef STAGE_QKV

    // bias -> Cs row-major [128][136]
    #pragma unroll
    for (int j = 0; j < 4; ++j) {
        const int lc = wc * 64 + j * 16 + l16;
        const float bj = b2f(bias[bn + lc]);
        #pragma unroll
        for (int i = 0; i < 4; ++i)
            #pragma unroll
            for (int r = 0; r < 4; ++r) {
                const int lr = wr * 64 + i * 16 + quad * 4 + r;
                Cs[lr * 136 + lc] = f2b(acc[i][j][r] + bj);
            }
    }
    __syncthreads();

    const int b_ = bm >> 10, sb16 = (bm & 1023) >> 4, kb64 = (bm & 1023) >> 6;
    if (bn < 2048) {                       // ---- Q or K region
        u16* out = (bn < 1024) ? Qblk : Kblk;
        const int hbase = (bn & 1023) >> 6;
        #pragma unroll
        for (int u = 0; u < 8; ++u) {
            const int g = u * 256 + tid;
            const int hh = g >> 10, rem = g & 1023;
            const int s16r = rem >> 7, rem2 = rem & 127;
            const int half = rem2 >> 6, lam = rem2 & 63;
            const int row = s16r * 16 + (lam & 15);
            const int col = hh * 64 + half * 32 + (lam >> 4) * 8;
            uint4 val = *(const uint4*)&Cs[row * 136 + col];
            const size_t gi = ((size_t)((b_ * 16 + hbase + hh) * 64 + sb16 + s16r)) * 1024
                            + half * 512 + (size_t)lam * 8;
            *(uint4*)&out[gi] = val;
        }
    } else {                               // ---- V region: transposed images
        const int hbase = (bn - 2048) >> 6;
        #pragma unroll
        for (int u = 0; u < 8; ++u) {
            const int g = u * 256 + tid;
            const int hh = g >> 10, rem = g & 1023;
            const int kt64r = rem >> 9, dt = (rem >> 7) & 3;
            const int half = (rem >> 6) & 1, lam = rem & 63;
            const int d = dt * 16 + (lam & 15);
            const int s0 = kt64r * 64 + half * 32 + (lam >> 4) * 8;
            union { uint4 q; u16 s[8]; } o;
            #pragma unroll
            for (int j = 0; j < 8; ++j) o.s[j] = Cs[(s0 + j) * 136 + hh * 64 + d];
            const size_t gi = ((size_t)((b_ * 16 + hbase + hh) * 16 + kb64 + kt64r)) * 4096
                            + dt * 1024 + half * 512 + (size_t)lam * 8;
            *(uint4*)&Vblk[gi] = o.q;
        }
    }
}

// ---------------------------------------------------------------------------
// MFMA flash attention. ROUND-8 CHANGE (single variable): 1-D grid 512 with
// XCD-chunked mapping — each XCD owns 8 complete (b,h) groups (all 8 qt
// blocks of each), so the K/V shared by those 8 blocks (512KB/group) is
// XCD-L2-resident instead of re-fetched from L3 by 8 different XCDs.
// Per-XCD working set: Q 2MB once + K/V prefetch window ~2MB < 4MB L2.
// Compute/staging byte-identical to round 7.
// ---------------------------------------------------------------------------
__global__ __launch_bounds__(512) void attn_mfma(
    const u16* __restrict__ Qblk, const u16* __restrict__ Kblk,
    const u16* __restrict__ Vblk, u16* __restrict__ ctx)
{
    __shared__ u16 Qf[8192];           // [w=8][half=2][lane][8]
    __shared__ u16 Kf[2][4096];        // [s16grp=4][half=2][lane][8]
    __shared__ u16 Vf[2][4096];        // [dt=4][half=2][lane][8]
    __shared__ u16 Ps[8 * 16 * 72];

    // XCD-chunked: fid%8 ~ XCD; XCD owns bh groups [xcd*8, xcd*8+8)
    const int fid = blockIdx.x;
    const int xcd = fid & 7, tt = fid >> 3;       // tt in [0,64)
    const int bh = (xcd << 3) + (tt >> 3);        // [0,64)
    const int qt = tt & 7;
    const int b = bh >> 4, h = bh & 15;

    const int tid = threadIdx.x;
    const int w = tid >> 6, lane = tid & 63;
    const int l16 = lane & 15, quad = lane >> 4;
    const size_t qrow0 = (size_t)(b * SEQ + qt * 128);
    const int hoff = h * DH;

    const u16* Qg = Qblk + ((size_t)(bh * 64 + qt * 8 + w)) * 1024 + (size_t)lane * 8;
    gl_lds16(Qg,       &Qf[w * 1024]);
    gl_lds16(Qg + 512, &Qf[w * 1024 + 512]);

    const u16* Kg = Kblk + ((size_t)(bh * 64)) * 1024 + (size_t)w * 512 + (size_t)lane * 8;
    const u16* Vg = Vblk + ((size_t)(bh * 16)) * 4096 + (size_t)w * 512 + (size_t)lane * 8;

    gl_lds16(Kg, &Kf[0][w * 512]);
    gl_lds16(Vg, &Vf[0][w * 512]);
    __syncthreads();

    bf16x8 aQ0 = *(const bf16x8*)&Qf[w * 1024 +       lane * 8];
    bf16x8 aQ1 = *(const bf16x8*)&Qf[w * 1024 + 512 + lane * 8];

    f32x4 O[4];
    #pragma unroll
    for (int dt = 0; dt < 4; ++dt) O[dt] = (f32x4){0.f, 0.f, 0.f, 0.f};
    float lacc[4] = {0.f, 0.f, 0.f, 0.f};

    for (int kt64 = 0; kt64 < SEQ / 64; ++kt64) {
        const int cur = kt64 & 1, nxt = cur ^ 1;
        if (kt64 + 1 < SEQ / 64) {
            gl_lds16(Kg + (size_t)(kt64 + 1) * 4096, &Kf[nxt][w * 512]);
            gl_lds16(Vg + (size_t)(kt64 + 1) * 4096, &Vf[nxt][w * 512]);
        }

        f32x4 St[4];
        #pragma unroll
        for (int t = 0; t < 4; ++t) {
            bf16x8 b0 = *(const bf16x8*)&Kf[cur][t * 1024 +       lane * 8];
            bf16x8 b1 = *(const bf16x8*)&Kf[cur][t * 1024 + 512 + lane * 8];
            f32x4 z = (f32x4){0.f, 0.f, 0.f, 0.f};
            z = __builtin_amdgcn_mfma_f32_16x16x32_bf16(aQ0, b0, z, 0, 0, 0);
            z = __builtin_amdgcn_mfma_f32_16x16x32_bf16(aQ1, b1, z, 0, 0, 0);
            St[t] = z;
        }

        #pragma unroll
        for (int t = 0; t < 4; ++t)
            #pragma unroll
            for (int r = 0; r < 4; ++r) {
                const float p = __expf(St[t][r] * 0.125f);
                lacc[r] += p;
                Ps[w * 1152 + (quad * 4 + r) * 72 + t * 16 + l16] = f2b_rh(p);
            }

        bf16x8 aP0 = *(const bf16x8*)&Ps[w * 1152 + l16 * 72 +  0 + quad * 8];
        bf16x8 aP1 = *(const bf16x8*)&Ps[w * 1152 + l16 * 72 + 32 + quad * 8];
        #pragma unroll
        for (int dt = 0; dt < 4; ++dt) {
            bf16x8 vv0 = *(const bf16x8*)&Vf[cur][dt * 1024 +       lane * 8];
            bf16x8 vv1 = *(const bf16x8*)&Vf[cur][dt * 1024 + 512 + lane * 8];
            O[dt] = __builtin_amdgcn_mfma_f32_16x16x32_bf16(aP0, vv0, O[dt], 0, 0, 0);
            O[dt] = __builtin_amdgcn_mfma_f32_16x16x32_bf16(aP1, vv1, O[dt], 0, 0, 0);
        }
        __syncthreads();
    }

    const size_t pbase = ((size_t)(qrow0 >> 7) * 32) << 12;
    #pragma unroll
    for (int r = 0; r < 4; ++r) {
        float s = lacc[r];
        s += __shfl_xor(s, 1);
        s += __shfl_xor(s, 2);
        s += __shfl_xor(s, 4);
        s += __shfl_xor(s, 8);
        const float inv = 1.0f / s;
        #pragma unroll
        for (int dt = 0; dt < 4; ++dt) {
            const int t = (hoff + dt * 16) >> 5;
            const int q = (((hoff + dt * 16) >> 3) & 3);
            const size_t idx = pbase + ((size_t)t << 12)
                             + ((w * 64 + q * 16 + quad * 4 + r) << 3) + (l16 & 7);
            const size_t idx2 = idx + (((size_t)(l16 >> 3)) << 7);
            ctx[idx2] = f2b(O[dt][r] * inv);
        }
    }
}

// ---------------------------------------------------------------------------
// MFMA GEMM, blocked A & B, 128x64 tile, K=1024; triple-buffered depth-2
// counted-vmcnt pipeline + XCD-chunked swizzle (validated round 7).
// ---------------------------------------------------------------------------
__global__ __launch_bounds__(256) void gemm_b64(
    const u16* __restrict__ Ab, const u16* __restrict__ Bb,
    const u16* __restrict__ bias, const u16* __restrict__ resid,
    u16* __restrict__ C, int N,
    int relu, int c_blocked, int resid_blocked)
{
    __shared__ uint4 smem4[2304];                 // A 3x8KB + B 3x4KB = 36KB
    u16* As = (u16*)smem4;
    u16* Bs = (u16*)smem4 + 12288;
    u16* Cs = (u16*)smem4;                        // [128][72] after loop

    const int tid = threadIdx.x;
    const int w = tid >> 6, lane = tid & 63;
    const int l16 = lane & 15, quad = lane >> 4;

    // XCD-chunked swizzle (grid 512 = 64 blocks/XCD, 512%8==0 -> bijective)
    const int fid = blockIdx.x;
    const int xcd = fid & 7, t = fid >> 3;        // t in [0,64)
    const int byi = ((xcd & 3) << 3) + (t & 7);   // M-panel [0,32)
    const int bxi = ((xcd >> 2) << 3) + (t >> 3); // N-block [0,16)
    const int bm = byi * 128, bn = bxi * 64;
    const int nkt = 32;                           // K = 1024 always

    const u16* At = Ab + ((size_t)(bm >> 7) * nkt << 12);
    const int bsub = ((bn >> 6) & 1) * 256;
    const u16* Bt = Bb + ((size_t)(bn >> 7) * nkt << 12);

    f32x4 acc[2][4];
    #pragma unroll
    for (int i = 0; i < 2; ++i)
        #pragma unroll
        for (int j = 0; j < 4; ++j)
            acc[i][j] = (f32x4){0.f, 0.f, 0.f, 0.f};

#define STAGE_B64(t_, bf) do {                                             \
        const size_t tb_ = (size_t)(t_) << 12;                             \
        gl_lds16(&At[tb_ + (w * 64 + lane) * 8],        As + (bf) * 4096 + w * 512);        \
        gl_lds16(&At[tb_ + (256 + w * 64 + lane) * 8],  As + (bf) * 4096 + 2048 + w * 512); \
        gl_lds16(&Bt[tb_ + (bsub + w * 64 + lane) * 8], Bs + (bf) * 2048 + w * 512);        \
    } while (0)

    STAGE_B64(0, 0);
    STAGE_B64(1, 1);
    asm volatile("s_waitcnt vmcnt(3)" ::: "memory");   // tile 0 landed; tile 1 in flight
    __builtin_amdgcn_s_barrier();

    int cur = 0, nb = 2;
    for (int kt = 0; kt < nkt; ++kt) {
        if (kt + 2 < nkt) STAGE_B64(kt + 2, nb);

        bf16x8 a[2], b[4];
        #pragma unroll
        for (int i = 0; i < 2; ++i)
            a[i] = *(const bf16x8*)&As[cur * 4096 + (((w * 2 + i) * 64) + quad * 16 + l16) * 8];
        #pragma unroll
        for (int j = 0; j < 4; ++j)
            b[j] = *(const bf16x8*)&Bs[cur * 2048 + ((j * 64) + quad * 16 + l16) * 8];

        #pragma unroll
        for (int i = 0; i < 2; ++i)
            #pragma unroll
            for (int j = 0; j < 4; ++j)
                acc[i][j] = __builtin_amdgcn_mfma_f32_16x16x32_bf16(a[i], b[j], acc[i][j], 0, 0, 0);

        if (kt + 2 < nkt) {
            asm volatile("s_waitcnt vmcnt(3)" ::: "memory");
            __builtin_amdgcn_s_barrier();
        } else if (kt + 1 < nkt) {
            asm volatile("s_waitcnt vmcnt(0)" ::: "memory");
            __builtin_amdgcn_s_barrier();
        }
        cur = cur == 2 ? 0 : cur + 1;
        nb  = nb  == 2 ? 0 : nb + 1;
    }
    __syncthreads();
#undef STAGE_B64

    #pragma unroll
    for (int j = 0; j < 4; ++j) {
        const int lc = j * 16 + l16;
        const int col = bn + lc;
        const float bj = bias ? b2f(bias[col]) : 0.f;
        #pragma unroll
        for (int i = 0; i < 2; ++i) {
            #pragma unroll
            for (int r = 0; r < 4; ++r) {
                const int lr = w * 32 + i * 16 + quad * 4 + r;
                float v = acc[i][j][r] + bj;
                if (resid) {
                    const size_t ri = resid_blocked ? blk_idx(bm + lr, col, N >> 5)
                                                    : (size_t)(bm + lr) * N + col;
                    v += b2f(resid[ri]);
                }
                if (relu) v = v > 0.f ? v : 0.f;
                Cs[lr * 72 + lc] = f2b(v);
            }
        }
    }
    __syncthreads();

    if (!c_blocked) {
        #pragma unroll
        for (int u = 0; u < 4; ++u) {
            const int g = u * 256 + tid;
            const int row = g >> 3, c16 = g & 7;
            uint4 val = *(const uint4*)&Cs[row * 72 + c16 * 8];
            *(uint4*)&C[(size_t)(bm + row) * N + bn + c16 * 8] = val;
        }
    } else {
        const size_t obase = ((size_t)((bm >> 7) * (N >> 5) + (bn >> 5))) << 12;
        #pragma unroll
        for (int u = 0; u < 4; ++u) {
            const int cc = u * 256 + tid;
            const int t2 = cc >> 9, c = cc & 511;
            const int row = ((c >> 6) & 7) * 16 + (c & 15);
            const int col = t2 * 32 + ((c >> 4) & 3) * 8;
            uint4 val = *(const uint4*)&Cs[row * 72 + col];
            *(uint4*)&C[obase + ((size_t)t2 << 12) + (size_t)c * 8] = val;
        }
    }
}

// ---------------------------------------------------------------------------
// LayerNorm, wave-per-row, 8 rows per 256-thr block, zero barriers.
// ---------------------------------------------------------------------------
__device__ __forceinline__ void ln8(
    const u16* __restrict__ X, const u16* __restrict__ gamma,
    const u16* __restrict__ beta, void* __restrict__ Y,
    int y_mode, int isf, int row0)
{
    const int tid = threadIdx.x;
    const int w = tid >> 6, lane = tid & 63;
    union U8 { uint4 q; u16 h[8]; };

    U8 ga, gb, ba, bb;
    ga.q = *(const uint4*)(gamma + lane * 16);
    gb.q = *(const uint4*)(gamma + lane * 16 + 8);
    ba.q = *(const uint4*)(beta  + lane * 16);
    bb.q = *(const uint4*)(beta  + lane * 16 + 8);
    float g[16], be[16];
    #pragma unroll
    for (int j = 0; j < 8; ++j) {
        g[j] = b2f(ga.h[j]);  g[8 + j] = b2f(gb.h[j]);
        be[j] = b2f(ba.h[j]); be[8 + j] = b2f(bb.h[j]);
    }

    #pragma unroll
    for (int it = 0; it < 2; ++it) {
        const int r = row0 + it * 4 + w;
        const u16* xp = X + (size_t)r * DM + lane * 16;
        U8 xa, xb;
        xa.q = *(const uint4*)xp;
        xb.q = *(const uint4*)(xp + 8);
        float xv[16], s = 0.f, s2 = 0.f;
        #pragma unroll
        for (int j = 0; j < 8; ++j) { xv[j] = b2f(xa.h[j]); xv[8 + j] = b2f(xb.h[j]); }
        #pragma unroll
        for (int j = 0; j < 16; ++j) { s += xv[j]; s2 += xv[j] * xv[j]; }
        #pragma unroll
        for (int d = 1; d < 64; d <<= 1) {
            s  += __shfl_xor(s, d);
            s2 += __shfl_xor(s2, d);
        }
        const float mu = s * (1.0f / DM);
        const float rstd = rsqrtf(s2 * (1.0f / DM) - mu * mu + 1e-5f);

        float y[16];
        #pragma unroll
        for (int j = 0; j < 16; ++j) y[j] = (xv[j] - mu) * rstd * g[j] + be[j];

        if (y_mode == 1) {
            #pragma unroll
            for (int c = 0; c < 2; ++c) {
                U8 o;
                #pragma unroll
                for (int j = 0; j < 8; ++j) o.h[j] = f2b(y[c * 8 + j]);
                *(uint4*)&((u16*)Y)[blk_idx(r, lane * 16 + c * 8, 32)] = o.q;
            }
        } else {
            if (isf) {
                float* yp = (float*)Y + (size_t)r * DM + lane * 16;
                #pragma unroll
                for (int c = 0; c < 4; ++c) {
                    float4 f; f.x = y[c*4]; f.y = y[c*4+1]; f.z = y[c*4+2]; f.w = y[c*4+3];
                    *(float4*)(yp + c * 4) = f;
                }
            } else {
                u16* yp = (u16*)Y + (size_t)r * DM + lane * 16;
                #pragma unroll
                for (int c = 0; c < 2; ++c) {
                    U8 o;
                    #pragma unroll
                    for (int j = 0; j < 8; ++j) o.h[j] = f2b(y[c * 8 + j]);
                    *(uint4*)(yp + c * 8) = o.q;
                }
            }
        }
    }
}

__global__ __launch_bounds__(256) void layernorm8(
    const u16* __restrict__ X, const u16* __restrict__ gamma,
    const u16* __restrict__ beta, void* __restrict__ Y,
    const uint32_t* __restrict__ xraw, int y_mode)
{
    const int isf = (y_mode == 2) ? detect_isf(xraw) : 0;
    ln8(X, gamma, beta, Y, y_mode, isf, blockIdx.x * 8);
}

// ---------------------------------------------------------------------------
extern "C" void kernel_launch(void* const* d_in, const int* in_sizes, int n_in,
                              void* d_out, int out_size, void* d_ws, size_t ws_size,
                              hipStream_t stream) {
    const void* x_raw   = d_in[0];
    const void* Wq_raw  = d_in[1];
    const void* bq_raw  = d_in[2];
    const void* Wk_raw  = d_in[3];
    const void* bk_raw  = d_in[4];
    const void* Wv_raw  = d_in[5];
    const void* bv_raw  = d_in[6];
    const void* Wo_raw  = d_in[7];
    const void* bo_raw  = d_in[8];
    const void* g1_raw  = d_in[9];
    const void* be1_raw = d_in[10];
    const void* W1_raw  = d_in[11];
    const void* b1_raw  = d_in[12];
    const void* W2_raw  = d_in[13];
    const void* b2_raw  = d_in[14];
    const void* g2_raw  = d_in[15];
    const void* be2_raw = d_in[16];

    char* ws = (char*)d_ws;
    const size_t MB = 1024 * 1024;
    u16* x_b    = (u16*)(ws + 1 * MB);        // blocked [4096,1024]  8 MB
    u16* WqkvB  = (u16*)(ws + 9 * MB);        // blocked B^T [3072,1024] 6 MB
    u16* WoB    = (u16*)(ws + 15 * MB);
    u16* W1B    = (u16*)(ws + 17 * MB);
    u16* W2B    = (u16*)(ws + 19 * MB);
    u16* vecs   = (u16*)(ws + 21 * MB);
    u16* bqkv_c = vecs;
    u16* bo_c   = vecs + 3072;
    u16* b1_c   = vecs + 4096;
    u16* b2_c   = vecs + 5120;
    u16* g1_c   = vecs + 6144;
    u16* be1_c  = vecs + 7168;
    u16* g2_c   = vecs + 8192;
    u16* be2_c  = vecs + 9216;
    u16* Qblk   = (u16*)(ws + 22 * MB);       // attn-native 8 MB
    u16* Kblk   = (u16*)(ws + 30 * MB);       // attn-native 8 MB
    u16* Vblk   = (u16*)(ws + 38 * MB);       // attn-native (V^T) 8 MB
    u16* ctxB   = (u16*)(ws + 48 * MB);       // GEMM-blocked 8 MB
    u16* res1   = (u16*)(ws + 56 * MB);       // row-major 8 MB
    u16* y1B    = Qblk;                       // dead after attention
    u16* hmidB  = Kblk;                       // dead after attention
    u16* res2   = res1;

    prep_all<<<8232, 256, 0, stream>>>(
        x_raw, Wq_raw, Wk_raw, Wv_raw, Wo_raw, W1_raw, W2_raw,
        bq_raw, bk_raw, bv_raw, bo_raw, b1_raw, b2_raw,
        g1_raw, be1_raw, g2_raw, be2_raw,
        x_b, WqkvB, WoB, W1B, W2B, vecs);

    // fused QKV projection -> attn-native Q/K/V (768 blocks, XCD-swizzled)
    gemm_qkv<<<768, 256, 0, stream>>>(x_b, WqkvB, bqkv_c, Qblk, Kblk, Vblk);

    // flash attention -> ctx GEMM-blocked (512 blocks, XCD-swizzled)
    attn_mfma<<<512, 512, 0, stream>>>(Qblk, Kblk, Vblk, ctxB);

    // tail GEMMs: 128x64 tile, 512 blocks each, XCD-swizzled
    gemm_b64<<<512, 256, 0, stream>>>(ctxB, WoB, bo_c, x_b, res1, DM, 0, 0, 1);
    layernorm8<<<ROWS / 8, 256, 0, stream>>>(res1, g1_c, be1_c, (void*)y1B, nullptr, 1);
    gemm_b64<<<512, 256, 0, stream>>>(y1B, W1B, b1_c, nullptr, hmidB, DM, 1, 1, 0);
    gemm_b64<<<512, 256, 0, stream>>>(hmidB, W2B, b2_c, y1B, res2, DM, 0, 0, 1);
    layernorm8<<<ROWS / 8, 256, 0, stream>>>(res2, g2_c, be2_c, d_out,
                                             (const uint32_t*)x_raw, 2);
}

// Round 9
// 244.508 us; speedup vs baseline: 1.0288x; 1.0288x over previous
//
#include <hip/hip_runtime.h>
#include <stdint.h>

// Problem constants (B=4, S=1024, D_MODEL=1024, H=16, D_HEAD=64, D_FF=1024)
#define BSZ 4
#define SEQ 1024
#define DM 1024
#define NH 16
#define DH 64
#define ROWS (BSZ * SEQ)   // 4096
#define QS3 3072

typedef unsigned short u16;
typedef short bf16x8 __attribute__((ext_vector_type(8)));
typedef float f32x4 __attribute__((ext_vector_type(4)));

__device__ __forceinline__ float b2f(u16 u) {
    union { uint32_t i; float f; } v; v.i = ((uint32_t)u) << 16; return v.f;
}
__device__ __forceinline__ u16 f2b(float f) {
    union { float f; uint32_t i; } v; v.f = f;
    uint32_t u = v.i;
    return (u16)((u + 0x7FFFu + ((u >> 16) & 1u)) >> 16);  // RTNE
}
__device__ __forceinline__ u16 f2b_rh(float f) {           // round-half-up (f >= 0)
    union { float f; uint32_t i; } v; v.f = f;
    return (u16)((v.i + 0x8000u) >> 16);
}

// Blocked fragment-order layout for [R, K] GEMM operands (tile 128x32 = 8KB).
__device__ __forceinline__ size_t blk_idx(int row, int col, int nkt) {
    return (((size_t)((row >> 7) * nkt + (col >> 5))) << 12)
         + ((((row >> 4) & 7) * 64 + ((col >> 3) & 3) * 16 + (row & 15)) << 3)
         + (col & 7);
}

typedef const __attribute__((address_space(1))) void gv_t;
typedef __attribute__((address_space(3))) void lv_t;
__device__ __forceinline__ void gl_lds16(const void* g, void* l) {
    __builtin_amdgcn_global_load_lds((gv_t*)g, (lv_t*)l, 16, 0, 0);
}

// ---------------------------------------------------------------------------
// Per-block dtype detection (no separate dispatch, no flag buffer).
// ---------------------------------------------------------------------------
__device__ __forceinline__ int detect_isf(const uint32_t* __restrict__ x) {
    const int lane = threadIdx.x & 63;
    const uint4 wv = *(const uint4*)(x + lane * 4);
    uint32_t ws[4] = {wv.x, wv.y, wv.z, wv.w};
    int c = 0;
    #pragma unroll
    for (int j = 0; j < 4; ++j) {
        uint32_t lo = ws[j] & 0xFFFFu;
        uint32_t e = (lo >> 7) & 0xFF;
        if ((e >= 100 && e <= 140) || lo == 0) c++;
    }
    #pragma unroll
    for (int d = 1; d < 64; d <<= 1) c += __shfl_xor(c, d);
    return c < 128;   // fewer than half sane -> fp32 input
}

// ---------------------------------------------------------------------------
// Fused preprocessing: ONE dispatch (unchanged).
// ---------------------------------------------------------------------------
__global__ __launch_bounds__(256) void prep_all(
    const void* x_raw, const void* Wq, const void* Wk, const void* Wv,
    const void* Wo, const void* W1, const void* W2,
    const void* bq, const void* bk, const void* bv, const void* bo,
    const void* b1, const void* b2, const void* g1, const void* be1,
    const void* g2, const void* be2,
    u16* __restrict__ x_b, u16* __restrict__ WqkvB, u16* __restrict__ WoB,
    u16* __restrict__ W1B, u16* __restrict__ W2B, u16* __restrict__ vecs)
{
    const int bid = blockIdx.x, tid = threadIdx.x;
    const int isf = detect_isf((const uint32_t*)x_raw);

    if (bid < 2048) {                      // ---- x convert to blocked
        const int gid = bid * 256 + tid;
        const int tile = gid >> 9, c = gid & 511;
        const int p = tile >> 5, t = tile & 31;
        const int r = p * 128 + ((c >> 6) & 7) * 16 + (c & 15);
        const int k = t * 32 + ((c >> 4) & 3) * 8;
        union { uint4 q; u16 s[8]; } o;
        if (isf) {
            const float* s = (const float*)x_raw + (size_t)r * DM + k;
            float4 f0 = *(const float4*)s;
            float4 f1 = *(const float4*)(s + 4);
            o.s[0] = f2b(f0.x); o.s[1] = f2b(f0.y); o.s[2] = f2b(f0.z); o.s[3] = f2b(f0.w);
            o.s[4] = f2b(f1.x); o.s[5] = f2b(f1.y); o.s[6] = f2b(f1.z); o.s[7] = f2b(f1.w);
        } else {
            o.q = *(const uint4*)((const u16*)x_raw + (size_t)r * DM + k);
        }
        *(uint4*)&x_b[(size_t)gid * 8] = o.q;
        return;
    }
    if (bid >= 8192) {                     // ---- small vectors
        const int i = (bid - 8192) * 256 + tid;   // [0, 10240)
        const int seg = i >> 10, off = i & 1023;
        const void* srcs[10] = {bq, bk, bv, bo, b1, b2, g1, be1, g2, be2};
        const void* s = srcs[seg];
        vecs[i] = isf ? f2b(((const float*)s)[off]) : ((const u16*)s)[off];
        return;
    }

    // ---- weight transposes (32x32 LDS tile)
    const void* src; u16* dst; int R, C, n_off, bx, by, z;
    if (bid < 5120) {                      // QKV: [H,1024,64]
        const int which = (bid - 2048) >> 10;     // 0,1,2
        const int lb = (bid - 2048) & 1023;
        src = which == 0 ? Wq : (which == 1 ? Wk : Wv);
        dst = WqkvB; R = DM; C = DH; n_off = which * 1024;
        bx = lb & 1; by = (lb >> 1) & 31; z = lb >> 6;
    } else {                               // square: [1024,1024]
        const int which = (bid - 5120) >> 10;     // 0,1,2
        const int lb = (bid - 5120) & 1023;
        src = which == 0 ? Wo : (which == 1 ? W1 : W2);
        dst = which == 0 ? WoB : (which == 1 ? W1B : W2B);
        R = DM; C = DM; n_off = 0;
        bx = lb & 31; by = (lb >> 5) & 31; z = 0;
    }

    __shared__ u16 Ts[32][33];
    const int cb = bx * 32, rb = by * 32;
    const int tr = tid >> 3, tc4 = (tid & 7) * 4;
    const size_t sbase = (size_t)z * R * C;

    u16 v[4];
    if (isf) {
        const float* s = (const float*)src + sbase + (size_t)(rb + tr) * C + cb + tc4;
        float4 f = *(const float4*)s;
        v[0] = f2b(f.x); v[1] = f2b(f.y); v[2] = f2b(f.z); v[3] = f2b(f.w);
    } else {
        const u16* s = (const u16*)src + sbase + (size_t)(rb + tr) * C + cb + tc4;
        ushort4 f = *(const ushort4*)s;
        v[0] = f.x; v[1] = f.y; v[2] = f.z; v[3] = f.w;
    }
    #pragma unroll
    for (int j = 0; j < 4; ++j) Ts[tc4 + j][tr] = v[j];
    __syncthreads();

    if (tid < 128) {
        const int np = tid & 31, qp = tid >> 5;
        const int n = n_off + z * C + cb + np;
        const int k = rb + qp * 8;
        union { uint4 q; u16 s[8]; } o;
        #pragma unroll
        for (int j = 0; j < 8; ++j) o.s[j] = Ts[np][qp * 8 + j];
        *(uint4*)&dst[blk_idx(n, k, 32)] = o.q;
    }
}

// ---------------------------------------------------------------------------
// QKV GEMM: blocked A,B; 128x128 tile; triple-buffered counted-vmcnt
// pipeline (depth-2). XCD-chunked swizzle (validated round 7).
// ---------------------------------------------------------------------------
__global__ __launch_bounds__(256) void gemm_qkv(
    const u16* __restrict__ Ab, const u16* __restrict__ Bb,
    const u16* __restrict__ bias,
    u16* __restrict__ Qblk, u16* __restrict__ Kblk, u16* __restrict__ Vblk)
{
    __shared__ uint4 smem4[3072];                 // A 3x8KB + B 3x8KB = 48KB
    u16* As = (u16*)smem4;
    u16* Bs = (u16*)smem4 + 12288;
    u16* Cs = (u16*)smem4;                        // [128][136] after loop

    const int tid = threadIdx.x;
    const int w = tid >> 6, lane = tid & 63;
    const int l16 = lane & 15, quad = lane >> 4;
    const int wr = w >> 1, wc = w & 1;

    // XCD-chunked swizzle (grid 768 = 96 blocks/XCD, 768%8==0 -> bijective)
    const int fid = blockIdx.x;
    const int xcd = fid & 7, t = fid >> 3;        // t in [0,96)
    const int byi = ((xcd & 3) << 3) + (t & 7);   // M-panel [0,32)
    const int bxi = (xcd >> 2) * 12 + (t >> 3);   // N-panel [0,24)
    const int bm = byi * 128, bn = bxi * 128;
    const int nkt = 32;

    const u16* At = Ab + ((size_t)(bm >> 7) * nkt << 12);
    const u16* Bt = Bb + ((size_t)(bn >> 7) * nkt << 12);

    f32x4 acc[4][4];
    #pragma unroll
    for (int i = 0; i < 4; ++i)
        #pragma unroll
        for (int j = 0; j < 4; ++j)
            acc[i][j] = (f32x4){0.f, 0.f, 0.f, 0.f};

#define STAGE_QKV(t_, bf) do {                                             \
        const size_t tb_ = (size_t)(t_) << 12;                             \
        gl_lds16(&At[tb_ + (w * 64 + lane) * 8],       As + (bf) * 4096 + w * 512);        \
        gl_lds16(&At[tb_ + (256 + w * 64 + lane) * 8], As + (bf) * 4096 + 2048 + w * 512); \
        gl_lds16(&Bt[tb_ + (w * 64 + lane) * 8],       Bs + (bf) * 4096 + w * 512);        \
        gl_lds16(&Bt[tb_ + (256 + w * 64 + lane) * 8], Bs + (bf) * 4096 + 2048 + w * 512); \
    } while (0)

    STAGE_QKV(0, 0);
    STAGE_QKV(1, 1);
    asm volatile("s_waitcnt vmcnt(4)" ::: "memory");   // tile 0 landed
    __builtin_amdgcn_s_barrier();

    int cur = 0, nb = 2;
    for (int kt = 0; kt < nkt; ++kt) {
        if (kt + 2 < nkt) STAGE_QKV(kt + 2, nb);

        bf16x8 a[4], b[4];
        #pragma unroll
        for (int i = 0; i < 4; ++i)
            a[i] = *(const bf16x8*)&As[cur * 4096 + (((wr * 4 + i) * 64) + quad * 16 + l16) * 8];
        #pragma unroll
        for (int j = 0; j < 4; ++j)
            b[j] = *(const bf16x8*)&Bs[cur * 4096 + (((wc * 4 + j) * 64) + quad * 16 + l16) * 8];

        #pragma unroll
        for (int i = 0; i < 4; ++i)
            #pragma unroll
            for (int j = 0; j < 4; ++j)
                acc[i][j] = __builtin_amdgcn_mfma_f32_16x16x32_bf16(a[i], b[j], acc[i][j], 0, 0, 0);

        if (kt + 2 < nkt) {
            asm volatile("s_waitcnt vmcnt(4)" ::: "memory");
            __builtin_amdgcn_s_barrier();
        } else if (kt + 1 < nkt) {
            asm volatile("s_waitcnt vmcnt(0)" ::: "memory");
            __builtin_amdgcn_s_barrier();
        }
        cur = cur == 2 ? 0 : cur + 1;
        nb  = nb  == 2 ? 0 : nb + 1;
    }
    __syncthreads();
#undef STAGE_QKV

    // bias -> Cs row-major [128][136]
    #pragma unroll
    for (int j = 0; j < 4; ++j) {
        const int lc = wc * 64 + j * 16 + l16;
        const float bj = b2f(bias[bn + lc]);
        #pragma unroll
        for (int i = 0; i < 4; ++i)
            #pragma unroll
            for (int r = 0; r < 4; ++r) {
                const int lr = wr * 64 + i * 16 + quad * 4 + r;
                Cs[lr * 136 + lc] = f2b(acc[i][j][r] + bj);
            }
    }
    __syncthreads();

    const int b_ = bm >> 10, sb16 = (bm & 1023) >> 4, kb64 = (bm & 1023) >> 6;
    if (bn < 2048) {                       // ---- Q or K region
        u16* out = (bn < 1024) ? Qblk : Kblk;
        const int hbase = (bn & 1023) >> 6;
        #pragma unroll
        for (int u = 0; u < 8; ++u) {
            const int g = u * 256 + tid;
            const int hh = g >> 10, rem = g & 1023;
            const int s16r = rem >> 7, rem2 = rem & 127;
            const int half = rem2 >> 6, lam = rem2 & 63;
            const int row = s16r * 16 + (lam & 15);
            const int col = hh * 64 + half * 32 + (lam >> 4) * 8;
            uint4 val = *(const uint4*)&Cs[row * 136 + col];
            const size_t gi = ((size_t)((b_ * 16 + hbase + hh) * 64 + sb16 + s16r)) * 1024
                            + half * 512 + (size_t)lam * 8;
            *(uint4*)&out[gi] = val;
        }
    } else {                               // ---- V region: transposed images
        const int hbase = (bn - 2048) >> 6;
        #pragma unroll
        for (int u = 0; u < 8; ++u) {
            const int g = u * 256 + tid;
            const int hh = g >> 10, rem = g & 1023;
            const int kt64r = rem >> 9, dt = (rem >> 7) & 3;
            const int half = (rem >> 6) & 1, lam = rem & 63;
            const int d = dt * 16 + (lam & 15);
            const int s0 = kt64r * 64 + half * 32 + (lam >> 4) * 8;
            union { uint4 q; u16 s[8]; } o;
            #pragma unroll
            for (int j = 0; j < 8; ++j) o.s[j] = Cs[(s0 + j) * 136 + hh * 64 + d];
            const size_t gi = ((size_t)((b_ * 16 + hbase + hh) * 16 + kb64 + kt64r)) * 4096
                            + dt * 1024 + half * 512 + (size_t)lam * 8;
            *(uint4*)&Vblk[gi] = o.q;
        }
    }
}

// ---------------------------------------------------------------------------
// MFMA flash attention over attn-native Q/K/V blocked buffers.
// ROUND-9: reverted to the (qt,h,b) 3-D grid — the round-8 XCD remap
// REGRESSED (+6.7us): K/V streams are L3-shared; concentrating 8 distinct
// groups per XCD made per-XCD demand burstier with no far-traffic saving.
// ---------------------------------------------------------------------------
__global__ __launch_bounds__(512) void attn_mfma(
    const u16* __restrict__ Qblk, const u16* __restrict__ Kblk,
    const u16* __restrict__ Vblk, u16* __restrict__ ctx)
{
    __shared__ u16 Qf[8192];           // [w=8][half=2][lane][8]
    __shared__ u16 Kf[2][4096];        // [s16grp=4][half=2][lane][8]
    __shared__ u16 Vf[2][4096];        // [dt=4][half=2][lane][8]
    __shared__ u16 Ps[8 * 16 * 72];

    const int qt = blockIdx.x, h = blockIdx.y, b = blockIdx.z;
    const int tid = threadIdx.x;
    const int w = tid >> 6, lane = tid & 63;
    const int l16 = lane & 15, quad = lane >> 4;
    const size_t qrow0 = (size_t)(b * SEQ + qt * 128);
    const int bh = b * NH + h;
    const int hoff = h * DH;

    const u16* Qg = Qblk + ((size_t)(bh * 64 + qt * 8 + w)) * 1024 + (size_t)lane * 8;
    gl_lds16(Qg,       &Qf[w * 1024]);
    gl_lds16(Qg + 512, &Qf[w * 1024 + 512]);

    const u16* Kg = Kblk + ((size_t)(bh * 64)) * 1024 + (size_t)w * 512 + (size_t)lane * 8;
    const u16* Vg = Vblk + ((size_t)(bh * 16)) * 4096 + (size_t)w * 512 + (size_t)lane * 8;

    gl_lds16(Kg, &Kf[0][w * 512]);
    gl_lds16(Vg, &Vf[0][w * 512]);
    __syncthreads();

    bf16x8 aQ0 = *(const bf16x8*)&Qf[w * 1024 +       lane * 8];
    bf16x8 aQ1 = *(const bf16x8*)&Qf[w * 1024 + 512 + lane * 8];

    f32x4 O[4];
    #pragma unroll
    for (int dt = 0; dt < 4; ++dt) O[dt] = (f32x4){0.f, 0.f, 0.f, 0.f};
    float lacc[4] = {0.f, 0.f, 0.f, 0.f};

    for (int kt64 = 0; kt64 < SEQ / 64; ++kt64) {
        const int cur = kt64 & 1, nxt = cur ^ 1;
        if (kt64 + 1 < SEQ / 64) {
            gl_lds16(Kg + (size_t)(kt64 + 1) * 4096, &Kf[nxt][w * 512]);
            gl_lds16(Vg + (size_t)(kt64 + 1) * 4096, &Vf[nxt][w * 512]);
        }

        f32x4 St[4];
        #pragma unroll
        for (int t = 0; t < 4; ++t) {
            bf16x8 b0 = *(const bf16x8*)&Kf[cur][t * 1024 +       lane * 8];
            bf16x8 b1 = *(const bf16x8*)&Kf[cur][t * 1024 + 512 + lane * 8];
            f32x4 z = (f32x4){0.f, 0.f, 0.f, 0.f};
            z = __builtin_amdgcn_mfma_f32_16x16x32_bf16(aQ0, b0, z, 0, 0, 0);
            z = __builtin_amdgcn_mfma_f32_16x16x32_bf16(aQ1, b1, z, 0, 0, 0);
            St[t] = z;
        }

        #pragma unroll
        for (int t = 0; t < 4; ++t)
            #pragma unroll
            for (int r = 0; r < 4; ++r) {
                const float p = __expf(St[t][r] * 0.125f);
                lacc[r] += p;
                Ps[w * 1152 + (quad * 4 + r) * 72 + t * 16 + l16] = f2b_rh(p);
            }

        bf16x8 aP0 = *(const bf16x8*)&Ps[w * 1152 + l16 * 72 +  0 + quad * 8];
        bf16x8 aP1 = *(const bf16x8*)&Ps[w * 1152 + l16 * 72 + 32 + quad * 8];
        #pragma unroll
        for (int dt = 0; dt < 4; ++dt) {
            bf16x8 vv0 = *(const bf16x8*)&Vf[cur][dt * 1024 +       lane * 8];
            bf16x8 vv1 = *(const bf16x8*)&Vf[cur][dt * 1024 + 512 + lane * 8];
            O[dt] = __builtin_amdgcn_mfma_f32_16x16x32_bf16(aP0, vv0, O[dt], 0, 0, 0);
            O[dt] = __builtin_amdgcn_mfma_f32_16x16x32_bf16(aP1, vv1, O[dt], 0, 0, 0);
        }
        __syncthreads();
    }

    const size_t pbase = ((size_t)(qrow0 >> 7) * 32) << 12;
    #pragma unroll
    for (int r = 0; r < 4; ++r) {
        float s = lacc[r];
        s += __shfl_xor(s, 1);
        s += __shfl_xor(s, 2);
        s += __shfl_xor(s, 4);
        s += __shfl_xor(s, 8);
        const float inv = 1.0f / s;
        #pragma unroll
        for (int dt = 0; dt < 4; ++dt) {
            const int t = (hoff + dt * 16) >> 5;
            const int q = (((hoff + dt * 16) >> 3) & 3);
            const size_t idx = pbase + ((size_t)t << 12)
                             + ((w * 64 + q * 16 + quad * 4 + r) << 3) + (l16 & 7);
            const size_t idx2 = idx + (((size_t)(l16 >> 3)) << 7);
            ctx[idx2] = f2b(O[dt][r] * inv);
        }
    }
}

// ---------------------------------------------------------------------------
// MFMA GEMM, blocked A & B, 128x64 tile, K=1024; triple-buffered depth-2
// counted-vmcnt pipeline + XCD-chunked swizzle (validated round 7).
// ---------------------------------------------------------------------------
__global__ __launch_bounds__(256) void gemm_b64(
    const u16* __restrict__ Ab, const u16* __restrict__ Bb,
    const u16* __restrict__ bias, const u16* __restrict__ resid,
    u16* __restrict__ C, int N,
    int relu, int c_blocked, int resid_blocked)
{
    __shared__ uint4 smem4[2304];                 // A 3x8KB + B 3x4KB = 36KB
    u16* As = (u16*)smem4;
    u16* Bs = (u16*)smem4 + 12288;
    u16* Cs = (u16*)smem4;                        // [128][72] after loop

    const int tid = threadIdx.x;
    const int w = tid >> 6, lane = tid & 63;
    const int l16 = lane & 15, quad = lane >> 4;

    // XCD-chunked swizzle (grid 512 = 64 blocks/XCD, 512%8==0 -> bijective)
    const int fid = blockIdx.x;
    const int xcd = fid & 7, t = fid >> 3;        // t in [0,64)
    const int byi = ((xcd & 3) << 3) + (t & 7);   // M-panel [0,32)
    const int bxi = ((xcd >> 2) << 3) + (t >> 3); // N-block [0,16)
    const int bm = byi * 128, bn = bxi * 64;
    const int nkt = 32;                           // K = 1024 always

    const u16* At = Ab + ((size_t)(bm >> 7) * nkt << 12);
    const int bsub = ((bn >> 6) & 1) * 256;
    const u16* Bt = Bb + ((size_t)(bn >> 7) * nkt << 12);

    f32x4 acc[2][4];
    #pragma unroll
    for (int i = 0; i < 2; ++i)
        #pragma unroll
        for (int j = 0; j < 4; ++j)
            acc[i][j] = (f32x4){0.f, 0.f, 0.f, 0.f};

#define STAGE_B64(t_, bf) do {                                             \
        const size_t tb_ = (size_t)(t_) << 12;                             \
        gl_lds16(&At[tb_ + (w * 64 + lane) * 8],        As + (bf) * 4096 + w * 512);        \
        gl_lds16(&At[tb_ + (256 + w * 64 + lane) * 8],  As + (bf) * 4096 + 2048 + w * 512); \
        gl_lds16(&Bt[tb_ + (bsub + w * 64 + lane) * 8], Bs + (bf) * 2048 + w * 512);        \
    } while (0)

    STAGE_B64(0, 0);
    STAGE_B64(1, 1);
    asm volatile("s_waitcnt vmcnt(3)" ::: "memory");   // tile 0 landed; tile 1 in flight
    __builtin_amdgcn_s_barrier();

    int cur = 0, nb = 2;
    for (int kt = 0; kt < nkt; ++kt) {
        if (kt + 2 < nkt) STAGE_B64(kt + 2, nb);

        bf16x8 a[2], b[4];
        #pragma unroll
        for (int i = 0; i < 2; ++i)
            a[i] = *(const bf16x8*)&As[cur * 4096 + (((w * 2 + i) * 64) + quad * 16 + l16) * 8];
        #pragma unroll
        for (int j = 0; j < 4; ++j)
            b[j] = *(const bf16x8*)&Bs[cur * 2048 + ((j * 64) + quad * 16 + l16) * 8];

        #pragma unroll
        for (int i = 0; i < 2; ++i)
            #pragma unroll
            for (int j = 0; j < 4; ++j)
                acc[i][j] = __builtin_amdgcn_mfma_f32_16x16x32_bf16(a[i], b[j], acc[i][j], 0, 0, 0);

        if (kt + 2 < nkt) {
            asm volatile("s_waitcnt vmcnt(3)" ::: "memory");
            __builtin_amdgcn_s_barrier();
        } else if (kt + 1 < nkt) {
            asm volatile("s_waitcnt vmcnt(0)" ::: "memory");
            __builtin_amdgcn_s_barrier();
        }
        cur = cur == 2 ? 0 : cur + 1;
        nb  = nb  == 2 ? 0 : nb + 1;
    }
    __syncthreads();
#undef STAGE_B64

    #pragma unroll
    for (int j = 0; j < 4; ++j) {
        const int lc = j * 16 + l16;
        const int col = bn + lc;
        const float bj = bias ? b2f(bias[col]) : 0.f;
        #pragma unroll
        for (int i = 0; i < 2; ++i) {
            #pragma unroll
            for (int r = 0; r < 4; ++r) {
                const int lr = w * 32 + i * 16 + quad * 4 + r;
                float v = acc[i][j][r] + bj;
                if (resid) {
                    const size_t ri = resid_blocked ? blk_idx(bm + lr, col, N >> 5)
                                                    : (size_t)(bm + lr) * N + col;
                    v += b2f(resid[ri]);
                }
                if (relu) v = v > 0.f ? v : 0.f;
                Cs[lr * 72 + lc] = f2b(v);
            }
        }
    }
    __syncthreads();

    if (!c_blocked) {
        #pragma unroll
        for (int u = 0; u < 4; ++u) {
            const int g = u * 256 + tid;
            const int row = g >> 3, c16 = g & 7;
            uint4 val = *(const uint4*)&Cs[row * 72 + c16 * 8];
            *(uint4*)&C[(size_t)(bm + row) * N + bn + c16 * 8] = val;
        }
    } else {
        const size_t obase = ((size_t)((bm >> 7) * (N >> 5) + (bn >> 5))) << 12;
        #pragma unroll
        for (int u = 0; u < 4; ++u) {
            const int cc = u * 256 + tid;
            const int t2 = cc >> 9, c = cc & 511;
            const int row = ((c >> 6) & 7) * 16 + (c & 15);
            const int col = t2 * 32 + ((c >> 4) & 3) * 8;
            uint4 val = *(const uint4*)&Cs[row * 72 + col];
            *(uint4*)&C[obase + ((size_t)t2 << 12) + (size_t)c * 8] = val;
        }
    }
}

// ---------------------------------------------------------------------------
// LayerNorm, wave-per-row, 8 rows per 256-thr block, zero barriers.
// ---------------------------------------------------------------------------
__device__ __forceinline__ void ln8(
    const u16* __restrict__ X, const u16* __restrict__ gamma,
    const u16* __restrict__ beta, void* __restrict__ Y,
    int y_mode, int isf, int row0)
{
    const int tid = threadIdx.x;
    const int w = tid >> 6, lane = tid & 63;
    union U8 { uint4 q; u16 h[8]; };

    U8 ga, gb, ba, bb;
    ga.q = *(const uint4*)(gamma + lane * 16);
    gb.q = *(const uint4*)(gamma + lane * 16 + 8);
    ba.q = *(const uint4*)(beta  + lane * 16);
    bb.q = *(const uint4*)(beta  + lane * 16 + 8);
    float g[16], be[16];
    #pragma unroll
    for (int j = 0; j < 8; ++j) {
        g[j] = b2f(ga.h[j]);  g[8 + j] = b2f(gb.h[j]);
        be[j] = b2f(ba.h[j]); be[8 + j] = b2f(bb.h[j]);
    }

    #pragma unroll
    for (int it = 0; it < 2; ++it) {
        const int r = row0 + it * 4 + w;
        const u16* xp = X + (size_t)r * DM + lane * 16;
        U8 xa, xb;
        xa.q = *(const uint4*)xp;
        xb.q = *(const uint4*)(xp + 8);
        float xv[16], s = 0.f, s2 = 0.f;
        #pragma unroll
        for (int j = 0; j < 8; ++j) { xv[j] = b2f(xa.h[j]); xv[8 + j] = b2f(xb.h[j]); }
        #pragma unroll
        for (int j = 0; j < 16; ++j) { s += xv[j]; s2 += xv[j] * xv[j]; }
        #pragma unroll
        for (int d = 1; d < 64; d <<= 1) {
            s  += __shfl_xor(s, d);
            s2 += __shfl_xor(s2, d);
        }
        const float mu = s * (1.0f / DM);
        const float rstd = rsqrtf(s2 * (1.0f / DM) - mu * mu + 1e-5f);

        float y[16];
        #pragma unroll
        for (int j = 0; j < 16; ++j) y[j] = (xv[j] - mu) * rstd * g[j] + be[j];

        if (y_mode == 1) {
            #pragma unroll
            for (int c = 0; c < 2; ++c) {
                U8 o;
                #pragma unroll
                for (int j = 0; j < 8; ++j) o.h[j] = f2b(y[c * 8 + j]);
                *(uint4*)&((u16*)Y)[blk_idx(r, lane * 16 + c * 8, 32)] = o.q;
            }
        } else {
            if (isf) {
                float* yp = (float*)Y + (size_t)r * DM + lane * 16;
                #pragma unroll
                for (int c = 0; c < 4; ++c) {
                    float4 f; f.x = y[c*4]; f.y = y[c*4+1]; f.z = y[c*4+2]; f.w = y[c*4+3];
                    *(float4*)(yp + c * 4) = f;
                }
            } else {
                u16* yp = (u16*)Y + (size_t)r * DM + lane * 16;
                #pragma unroll
                for (int c = 0; c < 2; ++c) {
                    U8 o;
                    #pragma unroll
                    for (int j = 0; j < 8; ++j) o.h[j] = f2b(y[c * 8 + j]);
                    *(uint4*)(yp + c * 8) = o.q;
                }
            }
        }
    }
}

__global__ __launch_bounds__(256) void layernorm8(
    const u16* __restrict__ X, const u16* __restrict__ gamma,
    const u16* __restrict__ beta, void* __restrict__ Y,
    const uint32_t* __restrict__ xraw, int y_mode)
{
    const int isf = (y_mode == 2) ? detect_isf(xraw) : 0;
    ln8(X, gamma, beta, Y, y_mode, isf, blockIdx.x * 8);
}

// ---------------------------------------------------------------------------
extern "C" void kernel_launch(void* const* d_in, const int* in_sizes, int n_in,
                              void* d_out, int out_size, void* d_ws, size_t ws_size,
                              hipStream_t stream) {
    const void* x_raw   = d_in[0];
    const void* Wq_raw  = d_in[1];
    const void* bq_raw  = d_in[2];
    const void* Wk_raw  = d_in[3];
    const void* bk_raw  = d_in[4];
    const void* Wv_raw  = d_in[5];
    const void* bv_raw  = d_in[6];
    const void* Wo_raw  = d_in[7];
    const void* bo_raw  = d_in[8];
    const void* g1_raw  = d_in[9];
    const void* be1_raw = d_in[10];
    const void* W1_raw  = d_in[11];
    const void* b1_raw  = d_in[12];
    const void* W2_raw  = d_in[13];
    const void* b2_raw  = d_in[14];
    const void* g2_raw  = d_in[15];
    const void* be2_raw = d_in[16];

    char* ws = (char*)d_ws;
    const size_t MB = 1024 * 1024;
    u16* x_b    = (u16*)(ws + 1 * MB);        // blocked [4096,1024]  8 MB
    u16* WqkvB  = (u16*)(ws + 9 * MB);        // blocked B^T [3072,1024] 6 MB
    u16* WoB    = (u16*)(ws + 15 * MB);
    u16* W1B    = (u16*)(ws + 17 * MB);
    u16* W2B    = (u16*)(ws + 19 * MB);
    u16* vecs   = (u16*)(ws + 21 * MB);
    u16* bqkv_c = vecs;
    u16* bo_c   = vecs + 3072;
    u16* b1_c   = vecs + 4096;
    u16* b2_c   = vecs + 5120;
    u16* g1_c   = vecs + 6144;
    u16* be1_c  = vecs + 7168;
    u16* g2_c   = vecs + 8192;
    u16* be2_c  = vecs + 9216;
    u16* Qblk   = (u16*)(ws + 22 * MB);       // attn-native 8 MB
    u16* Kblk   = (u16*)(ws + 30 * MB);       // attn-native 8 MB
    u16* Vblk   = (u16*)(ws + 38 * MB);       // attn-native (V^T) 8 MB
    u16* ctxB   = (u16*)(ws + 48 * MB);       // GEMM-blocked 8 MB
    u16* res1   = (u16*)(ws + 56 * MB);       // row-major 8 MB
    u16* y1B    = Qblk;                       // dead after attention
    u16* hmidB  = Kblk;                       // dead after attention
    u16* res2   = res1;

    prep_all<<<8232, 256, 0, stream>>>(
        x_raw, Wq_raw, Wk_raw, Wv_raw, Wo_raw, W1_raw, W2_raw,
        bq_raw, bk_raw, bv_raw, bo_raw, b1_raw, b2_raw,
        g1_raw, be1_raw, g2_raw, be2_raw,
        x_b, WqkvB, WoB, W1B, W2B, vecs);

    // fused QKV projection -> attn-native Q/K/V (768 blocks, XCD-swizzled)
    gemm_qkv<<<768, 256, 0, stream>>>(x_b, WqkvB, bqkv_c, Qblk, Kblk, Vblk);

    // flash attention -> ctx GEMM-blocked (3-D grid, round-7 mapping)
    attn_mfma<<<dim3(SEQ / 128, NH, BSZ), 512, 0, stream>>>(Qblk, Kblk, Vblk, ctxB);

    // tail GEMMs: 128x64 tile, 512 blocks each, XCD-swizzled
    gemm_b64<<<512, 256, 0, stream>>>(ctxB, WoB, bo_c, x_b, res1, DM, 0, 0, 1);
    layernorm8<<<ROWS / 8, 256, 0, stream>>>(res1, g1_c, be1_c, (void*)y1B, nullptr, 1);
    gemm_b64<<<512, 256, 0, stream>>>(y1B, W1B, b1_c, nullptr, hmidB, DM, 1, 1, 0);
    gemm_b64<<<512, 256, 0, stream>>>(hmidB, W2B, b2_c, y1B, res2, DM, 0, 0, 1);
    layernorm8<<<ROWS / 8, 256, 0, stream>>>(res2, g2_c, be2_c, d_out,
                                             (const uint32_t*)x_raw, 2);
}